// Round 1
// baseline (380.944 us; speedup 1.0000x reference)
//
#include <hip/hip_runtime.h>

// Shapes: x[B=128][CIN=16][F=512][N=32], W1[N][16][16][2], b1[N][16],
//         W2[N][16][16], b2[N][16].  out[B][16][F][64] (identity permute).
#define B_    128
#define CIN_  16
#define COUT_ 16
#define F_    512
#define N_    32
#define FC    16   // f-values per block tile

// ---------------------------------------------------------------------------
// Kernel 1: fold the two channel mixes.
// Weff[n][c][i][k] = sum_o W1[n][i][o][k] * W2[n][o][c]   (layout: 32 floats
// contiguous per (n,c) so the main kernel loads 8x float4 per channel)
// beff[n][c]       = sum_o b1[n][o] * W2[n][o][c] + b2[n][c]
// ---------------------------------------------------------------------------
__global__ __launch_bounds__(256) void weff_kernel(
    const float* __restrict__ W1, const float* __restrict__ b1,
    const float* __restrict__ W2, const float* __restrict__ b2,
    float* __restrict__ Weff, float* __restrict__ beff) {
  const int t = blockIdx.x * 256 + threadIdx.x;  // 0..8191 -> (n,c,i)
  const int n = t >> 8, c = (t >> 4) & 15, i = t & 15;
  const float* w1 = W1 + (size_t)((n * 16 + i) * 16) * 2;  // [o][k]
  const float* w2 = W2 + (size_t)(n * 16) * 16 + c;        // stride 16 over o
  float a0 = 0.f, a1 = 0.f;
#pragma unroll
  for (int o = 0; o < 16; ++o) {
    const float m = w2[o * 16];
    a0 += w1[o * 2 + 0] * m;
    a1 += w1[o * 2 + 1] * m;
  }
  Weff[(size_t)((n * 16 + c) * 16 + i) * 2 + 0] = a0;
  Weff[(size_t)((n * 16 + c) * 16 + i) * 2 + 1] = a1;
  if (t < 512) {  // t -> (n,c)
    const int nn = t >> 4, cc = t & 15;
    float s = b2[nn * 16 + cc];
#pragma unroll
    for (int o = 0; o < 16; ++o)
      s += b1[nn * 16 + o] * W2[(nn * 16 + o) * 16 + cc];
    beff[t] = s;
  }
}

// ---------------------------------------------------------------------------
// Kernel 2: out[b][c][f][2n+k] = sum_i x[b][i][f][n]*Weff[n][c][i][k] + beff
// Block: 256 threads = (cg 0..7) x (n 0..31); each thread covers c = cg, cg+8.
// One block per (b, f-chunk of 16).  x tile staged in LDS, layout
// xs[i>>2][df][n][i&3] so compute reads are sequential ds_read_b128.
// ---------------------------------------------------------------------------
__global__ __launch_bounds__(256) void up_kernel(
    const float* __restrict__ x, const float* __restrict__ Weff,
    const float* __restrict__ beff, float* __restrict__ out) {
  __shared__ float xs[4 * FC * 32 * 4];  // 32 KiB: [g][df][n][r], i = 4g+r

  const int bid = blockIdx.x;
  const int b   = bid >> 5;          // 4096 blocks / 32 chunks
  const int f0  = (bid & 31) * FC;
  const int t   = threadIdx.x;

  // ---- stage x[b][:][f0:f0+16][:] with 4x4 register transpose ----
#pragma unroll
  for (int s = 0; s < 2; ++s) {
    const int q  = t + 256 * s;          // 0..511 -> (g, df, n4)
    const int g  = q >> 7;
    const int df = (q >> 3) & 15;
    const int n4 = q & 7;
    const float* src =
        x + ((size_t)(b * CIN_ + 4 * g) * F_ + (f0 + df)) * N_ + n4 * 4;
    const float4 v0 = *(const float4*)(src + 0 * (size_t)F_ * N_);
    const float4 v1 = *(const float4*)(src + 1 * (size_t)F_ * N_);
    const float4 v2 = *(const float4*)(src + 2 * (size_t)F_ * N_);
    const float4 v3 = *(const float4*)(src + 3 * (size_t)F_ * N_);
    float* dst = xs + ((g * FC + df) * 32 + n4 * 4) * 4;
    ((float4*)dst)[0] = make_float4(v0.x, v1.x, v2.x, v3.x);
    ((float4*)dst)[1] = make_float4(v0.y, v1.y, v2.y, v3.y);
    ((float4*)dst)[2] = make_float4(v0.z, v1.z, v2.z, v3.z);
    ((float4*)dst)[3] = make_float4(v0.w, v1.w, v2.w, v3.w);
  }

  // ---- per-thread fused weights in registers (c = cg and cg+8) ----
  const int n  = t & 31;
  const int cg = t >> 5;
  float w[2][32];
  float bias[2];
#pragma unroll
  for (int cc = 0; cc < 2; ++cc) {
    const int c = cg + cc * 8;
    const float4* wp = (const float4*)(Weff + (size_t)(n * 16 + c) * 32);
#pragma unroll
    for (int j = 0; j < 8; ++j) {
      const float4 v = wp[j];
      w[cc][4 * j + 0] = v.x;
      w[cc][4 * j + 1] = v.y;
      w[cc][4 * j + 2] = v.z;
      w[cc][4 * j + 3] = v.w;
    }
    bias[cc] = beff[n * 16 + c];
  }

  __syncthreads();

  float* o0 = out + ((size_t)(b * COUT_ + cg) * F_ + f0) * 64 + 2 * n;
  float* o1 = o0 + (size_t)8 * F_ * 64;

#pragma unroll 4
  for (int df = 0; df < FC; ++df) {
    float a00 = bias[0], a01 = bias[0];
    float a10 = bias[1], a11 = bias[1];
#pragma unroll
    for (int g = 0; g < 4; ++g) {
      const float4 xv = *(const float4*)(xs + ((g * FC + df) * 32 + n) * 4);
      const float xi[4] = {xv.x, xv.y, xv.z, xv.w};
#pragma unroll
      for (int r = 0; r < 4; ++r) {
        const int i = 4 * g + r;
        a00 += xi[r] * w[0][2 * i + 0];
        a01 += xi[r] * w[0][2 * i + 1];
        a10 += xi[r] * w[1][2 * i + 0];
        a11 += xi[r] * w[1][2 * i + 1];
      }
    }
    *(float2*)(o0 + df * 64) = make_float2(a00, a01);
    *(float2*)(o1 + df * 64) = make_float2(a10, a11);
  }
}

extern "C" void kernel_launch(void* const* d_in, const int* in_sizes, int n_in,
                              void* d_out, int out_size, void* d_ws, size_t ws_size,
                              hipStream_t stream) {
  const float* x  = (const float*)d_in[0];
  const float* W1 = (const float*)d_in[1];
  const float* b1 = (const float*)d_in[2];
  const float* W2 = (const float*)d_in[3];
  const float* b2 = (const float*)d_in[4];
  float* out = (float*)d_out;

  float* Weff = (float*)d_ws;                    // 16384 floats
  float* beff = Weff + N_ * COUT_ * CIN_ * 2;    // 512 floats

  weff_kernel<<<32, 256, 0, stream>>>(W1, b1, W2, b2, Weff, beff);
  up_kernel<<<B_ * (F_ / FC), 256, 0, stream>>>(x, Weff, beff, out);
}

// Round 3
// 366.920 us; speedup vs baseline: 1.0382x; 1.0382x over previous
//
#include <hip/hip_runtime.h>

// Shapes: x[B=128][CIN=16][F=512][N=32], W1[N][16][16][2], b1[N][16],
//         W2[N][16][16], b2[N][16].  out[B][16][F][64] (identity permute).
#define B_    128
#define CIN_  16
#define COUT_ 16
#define F_    512
#define N_    32
#define FC    16   // f-values per block tile

typedef float f32x2 __attribute__((ext_vector_type(2)));

// ---------------------------------------------------------------------------
// Kernel 1: fold the two channel mixes.
// Weff[n][c][i][k] = sum_o W1[n][i][o][k] * W2[n][o][c]
// beff[n][c]       = sum_o b1[n][o] * W2[n][o][c] + b2[n][c]
// ---------------------------------------------------------------------------
__global__ __launch_bounds__(256) void weff_kernel(
    const float* __restrict__ W1, const float* __restrict__ b1,
    const float* __restrict__ W2, const float* __restrict__ b2,
    float* __restrict__ Weff, float* __restrict__ beff) {
  const int t = blockIdx.x * 256 + threadIdx.x;  // 0..8191 -> (n,c,i)
  const int n = t >> 8, c = (t >> 4) & 15, i = t & 15;
  const float* w1 = W1 + (size_t)((n * 16 + i) * 16) * 2;  // [o][k]
  const float* w2 = W2 + (size_t)(n * 16) * 16 + c;        // stride 16 over o
  float a0 = 0.f, a1 = 0.f;
#pragma unroll
  for (int o = 0; o < 16; ++o) {
    const float m = w2[o * 16];
    a0 += w1[o * 2 + 0] * m;
    a1 += w1[o * 2 + 1] * m;
  }
  Weff[(size_t)((n * 16 + c) * 16 + i) * 2 + 0] = a0;
  Weff[(size_t)((n * 16 + c) * 16 + i) * 2 + 1] = a1;
  if (t < 512) {  // t -> (n,c)
    const int nn = t >> 4, cc = t & 15;
    float s = b2[nn * 16 + cc];
#pragma unroll
    for (int o = 0; o < 16; ++o)
      s += b1[nn * 16 + o] * W2[(nn * 16 + o) * 16 + cc];
    beff[t] = s;
  }
}

// ---------------------------------------------------------------------------
// Kernel 2: out[b][c][f][2n+k] = sum_i x[b][i][f][n]*Weff[n][c][i][k] + beff
// Block: 256 threads = (cg 0..7) x (n 0..31); each thread covers c = cg, cg+8.
// One block per (b, f-chunk of 16).
// LDS holds 16B units keyed by (g, df, n): unit u = (g*16+df)*32 + n, stored
// at xs4[u ^ (df&7)].  The XOR spreads the staging writes (lane stride 64 B,
// otherwise a 32-words-per-bank collision) evenly to the b128 optimum of
// 8 words/bank; compute reads permute within a contiguous 512 B row ->
// still conflict-free.
// ---------------------------------------------------------------------------
__global__ __launch_bounds__(256) void up_kernel(
    const float* __restrict__ x, const float* __restrict__ Weff,
    const float* __restrict__ beff, float* __restrict__ out) {
  __shared__ float4 xs4[4 * FC * 32];  // 32 KiB

  const int bid = blockIdx.x;
  const int b   = bid >> 5;          // 4096 blocks / 32 chunks
  const int f0  = (bid & 31) * FC;
  const int t   = threadIdx.x;

  // ---- stage x[b][:][f0:f0+16][:] with 4x4 register transpose ----
#pragma unroll
  for (int s = 0; s < 2; ++s) {
    const int q  = t + 256 * s;          // 0..511 -> (g, df, n4)
    const int g  = q >> 7;
    const int df = (q >> 3) & 15;
    const int n4 = q & 7;
    const float* src =
        x + ((size_t)(b * CIN_ + 4 * g) * F_ + (f0 + df)) * N_ + n4 * 4;
    const float4 v0 = *(const float4*)(src + 0 * (size_t)F_ * N_);
    const float4 v1 = *(const float4*)(src + 1 * (size_t)F_ * N_);
    const float4 v2 = *(const float4*)(src + 2 * (size_t)F_ * N_);
    const float4 v3 = *(const float4*)(src + 3 * (size_t)F_ * N_);
    const int u0  = (g * FC + df) * 32 + n4 * 4;
    const int key = df & 7;
    xs4[(u0 + 0) ^ key] = make_float4(v0.x, v1.x, v2.x, v3.x);
    xs4[(u0 + 1) ^ key] = make_float4(v0.y, v1.y, v2.y, v3.y);
    xs4[(u0 + 2) ^ key] = make_float4(v0.z, v1.z, v2.z, v3.z);
    xs4[(u0 + 3) ^ key] = make_float4(v0.w, v1.w, v2.w, v3.w);
  }

  // ---- per-thread fused weights in registers (c = cg and cg+8) ----
  const int n  = t & 31;
  const int cg = t >> 5;
  float w[2][32];
  float bias[2];
#pragma unroll
  for (int cc = 0; cc < 2; ++cc) {
    const int c = cg + cc * 8;
    const float4* wp = (const float4*)(Weff + (size_t)(n * 16 + c) * 32);
#pragma unroll
    for (int j = 0; j < 8; ++j) {
      const float4 v = wp[j];
      w[cc][4 * j + 0] = v.x;
      w[cc][4 * j + 1] = v.y;
      w[cc][4 * j + 2] = v.z;
      w[cc][4 * j + 3] = v.w;
    }
    bias[cc] = beff[n * 16 + c];
  }

  __syncthreads();

  float* o0 = out + ((size_t)(b * COUT_ + cg) * F_ + f0) * 64 + 2 * n;
  float* o1 = o0 + (size_t)8 * F_ * 64;

#pragma unroll 4
  for (int df = 0; df < FC; ++df) {
    float a00 = bias[0], a01 = bias[0];
    float a10 = bias[1], a11 = bias[1];
#pragma unroll
    for (int g = 0; g < 4; ++g) {
      const float4 xv = xs4[((g * FC + df) * 32 + n) ^ (df & 7)];
      const float xi[4] = {xv.x, xv.y, xv.z, xv.w};
#pragma unroll
      for (int r = 0; r < 4; ++r) {
        const int i = 4 * g + r;
        a00 += xi[r] * w[0][2 * i + 0];
        a01 += xi[r] * w[0][2 * i + 1];
        a10 += xi[r] * w[1][2 * i + 0];
        a11 += xi[r] * w[1][2 * i + 1];
      }
    }
    f32x2 r0; r0.x = a00; r0.y = a01;
    f32x2 r1; r1.x = a10; r1.y = a11;
    __builtin_nontemporal_store(r0, (f32x2*)(o0 + df * 64));
    __builtin_nontemporal_store(r1, (f32x2*)(o1 + df * 64));
  }
}

extern "C" void kernel_launch(void* const* d_in, const int* in_sizes, int n_in,
                              void* d_out, int out_size, void* d_ws, size_t ws_size,
                              hipStream_t stream) {
  const float* x  = (const float*)d_in[0];
  const float* W1 = (const float*)d_in[1];
  const float* b1 = (const float*)d_in[2];
  const float* W2 = (const float*)d_in[3];
  const float* b2 = (const float*)d_in[4];
  float* out = (float*)d_out;

  float* Weff = (float*)d_ws;                    // 16384 floats
  float* beff = Weff + N_ * COUT_ * CIN_ * 2;    // 512 floats

  weff_kernel<<<32, 256, 0, stream>>>(W1, b1, W2, b2, Weff, beff);
  up_kernel<<<B_ * (F_ / FC), 256, 0, stream>>>(x, Weff, beff, out);
}